// Round 1
// baseline (1936.225 us; speedup 1.0000x reference)
//
#include <hip/hip_runtime.h>
#include <cstddef>

#define NA 20000
#define NW 100000
#define HH 128
#define DA 64
#define E_CR 400000
#define E_IN 600000
#define E_CO 300000

// ---------------- dense linear: Y[M,N] = act(X[M,ldx(+off)] @ W[K,N] + b) ----------------
// Thread j holds W column j in registers; X rows read via block-uniform scalar loads.
template<int K, int N, int ACT, int ACC>
__global__ __launch_bounds__(N, 2) void k_linear(
    const float* __restrict__ X, int ldx,
    const float* __restrict__ W,
    const float* __restrict__ bias,
    float* __restrict__ Y, int ldy, int M)
{
    const int j = threadIdx.x;
    float w[K];
#pragma unroll
    for (int k = 0; k < K; ++k) w[k] = W[(size_t)k * N + j];

    const int ROWS = 4;
    for (int r0 = blockIdx.x * ROWS; r0 < M; r0 += gridDim.x * ROWS) {
        const float* xp[ROWS];
        float acc[ROWS];
#pragma unroll
        for (int i = 0; i < ROWS; ++i) {
            int r = r0 + i; int rc = r < M ? r : M - 1;
            xp[i] = X + (size_t)rc * ldx;
            if (ACC) acc[i] = Y[(size_t)rc * ldy + j];
            else     acc[i] = bias ? bias[j] : 0.f;
        }
#pragma unroll
        for (int k = 0; k < K; ++k) {
#pragma unroll
            for (int i = 0; i < ROWS; ++i)
                acc[i] = fmaf(xp[i][k], w[k], acc[i]);
        }
#pragma unroll
        for (int i = 0; i < ROWS; ++i) {
            int r = r0 + i;
            if (r < M) {
                float v = acc[i];
                if (ACT == 1) v = v > 0.f ? v : 0.f;
                Y[(size_t)r * ldy + j] = v;
            }
        }
    }
}

// ---------------- gemv: out[r] = dot(X[r, 0:128], v) + bias ----------------
__global__ __launch_bounds__(256) void k_gemv128(
    const float* __restrict__ X, int ldx, const float* __restrict__ v,
    const float* __restrict__ bias, float* __restrict__ out, int M)
{
    int lane = threadIdx.x & 63;
    int w = threadIdx.x >> 6;
    int r = blockIdx.x * 4 + w;
    if (r >= M) return;
    const float* xr = X + (size_t)r * ldx;
    float s = xr[lane] * v[lane] + xr[lane + 64] * v[lane + 64];
#pragma unroll
    for (int o = 32; o; o >>= 1) s += __shfl_xor(s, o, 64);
    if (lane == 0) out[r] = s + (bias ? bias[0] : 0.f);
}

// ---------------- vd[k] = sum_j W[k][j] * a[j] ----------------
__global__ void k_wv(const float* __restrict__ W, const float* __restrict__ a,
                     float* __restrict__ vd)
{
    __shared__ float sa[HH];
    sa[threadIdx.x] = a[threadIdx.x];
    __syncthreads();
    float s = 0.f;
    for (int jj = 0; jj < HH; ++jj) s += W[(size_t)threadIdx.x * HH + jj] * sa[jj];
    vd[threadIdx.x] = s;
}

// ---------------- CSR build ----------------
__global__ void k_hist(const int* __restrict__ dst, int E, int L, int* __restrict__ deg)
{
    int i = blockIdx.x * blockDim.x + threadIdx.x;
    int T = E + L;
    if (i >= T) return;
    int d = (i < E) ? dst[i] : (i - E);
    atomicAdd(&deg[d], 1);
}

__global__ void k_scan1(const int* __restrict__ deg, int n,
                        int* __restrict__ rowptr, int* __restrict__ bsum)
{
    __shared__ int sm[256];
    int t = threadIdx.x;
    int i = blockIdx.x * 256 + t;
    int v = (i < n) ? deg[i] : 0;
    int x = v;
    sm[t] = x;
    __syncthreads();
    for (int o = 1; o < 256; o <<= 1) {
        int y = (t >= o) ? sm[t - o] : 0;
        __syncthreads();
        x += y;
        sm[t] = x;
        __syncthreads();
    }
    if (i < n) rowptr[i] = x - v;
    if (t == 255) bsum[blockIdx.x] = x;
}

__global__ void k_scan2(int* __restrict__ bsum, int nb)
{
    if (threadIdx.x || blockIdx.x) return;
    int run = 0;
    for (int b = 0; b < nb; ++b) { int t = bsum[b]; bsum[b] = run; run += t; }
}

__global__ void k_scan3(int* __restrict__ rowptr, int* __restrict__ cursor,
                        const int* __restrict__ bsum, int n, int Etot)
{
    int i = blockIdx.x * 256 + threadIdx.x;
    if (i < n) {
        int v = rowptr[i] + bsum[i >> 8];
        rowptr[i] = v;
        cursor[i] = v;
    }
    if (i == 0) rowptr[n] = Etot;
}

__global__ void k_scatter(const int* __restrict__ src, const int* __restrict__ dstp,
                          int E, int L, int* __restrict__ cursor, int* __restrict__ esrc)
{
    int i = blockIdx.x * blockDim.x + threadIdx.x;
    int T = E + L;
    if (i >= T) return;
    int s, d;
    if (i < E) { s = src[i]; d = dstp[i]; }
    else       { s = i - E;  d = i - E; }
    int p = atomicAdd(&cursor[d], 1);
    esrc[p] = s;
}

// ---------------- GAT aggregation (one block per dst node) ----------------
template<int ELU>
__global__ __launch_bounds__(128) void k_aggregate(
    const int* __restrict__ rowptr, const int* __restrict__ esrc,
    const float* __restrict__ hs, const float* __restrict__ ss,
    const float* __restrict__ sd, const float* __restrict__ bias,
    float* __restrict__ out, int n)
{
    int d = blockIdx.x;
    if (d >= n) return;
    int j = threadIdx.x;
    int i0 = rowptr[d], i1 = rowptr[d + 1];
    float sdv = sd[d];
    float den = 0.f, acc = 0.f;
    for (int i = i0; i < i1; ++i) {
        int s = esrc[i];
        float l = ss[s] + sdv;
        l = l < 0.f ? 0.2f * l : l;
        float e = __expf(l);
        den += e;
        acc += e * hs[(size_t)s * HH + j];
    }
    float o = acc / (den + 1e-16f) + bias[j];
    if (ELU) o = o > 0.f ? o : expm1f(o);
    out[(size_t)d * HH + j] = o;
}

// ---------------- launcher ----------------
extern "C" void kernel_launch(void* const* d_in, const int* in_sizes, int n_in,
                              void* d_out, int out_size, void* d_ws, size_t ws_size,
                              hipStream_t stream)
{
    const float* artist = (const float*)d_in[0];
    const float* workf  = (const float*)d_in[1];
    const float* a_w1 = (const float*)d_in[2];  const float* a_b1 = (const float*)d_in[3];
    const float* a_w2 = (const float*)d_in[4];  const float* a_b2 = (const float*)d_in[5];
    const float* w_w1 = (const float*)d_in[6];  const float* w_b1 = (const float*)d_in[7];
    const float* w_w2 = (const float*)d_in[8];  const float* w_b2 = (const float*)d_in[9];
    const float* cr_W = (const float*)d_in[10]; const float* cr_b = (const float*)d_in[11];
    const float* cr_as = (const float*)d_in[12]; const float* cr_ad = (const float*)d_in[13];
    const float* in_W = (const float*)d_in[14]; const float* in_b = (const float*)d_in[15];
    const float* in_as = (const float*)d_in[16]; const float* in_ad = (const float*)d_in[17];
    const float* co_W = (const float*)d_in[18]; const float* co_b = (const float*)d_in[19];
    const float* co_as = (const float*)d_in[20]; const float* co_ad = (const float*)d_in[21];
    const float* p_w1 = (const float*)d_in[22]; const float* p_b1 = (const float*)d_in[23];
    const float* p_w2 = (const float*)d_in[24]; const float* p_b2 = (const float*)d_in[25];
    const float* p_w3 = (const float*)d_in[26]; const float* p_b3 = (const float*)d_in[27];
    const int* e_cr = (const int*)d_in[28];
    const int* e_cb = (const int*)d_in[29];
    const int* e_in = (const int*)d_in[30];
    const int* e_co = (const int*)d_in[31];

    char* wsp = (char*)d_ws;
    size_t off = 0;
    auto alloc = [&](size_t bytes) -> void* {
        void* p = wsp + off;
        off += (bytes + 255) / 256 * 256;
        return p;
    };
    float* ax  = (float*)alloc((size_t)NA * HH * 4);
    float* wx  = (float*)alloc((size_t)NW * HH * 4);
    float* hs  = (float*)alloc((size_t)NW * HH * 4);  // also predictor h1 [NA,256]
    float* au  = (float*)alloc((size_t)NA * HH * 4);  // also predictor h2
    float* ac  = (float*)alloc((size_t)NA * HH * 4);
    float* ssb = (float*)alloc((size_t)NW * 4);
    float* sdb = (float*)alloc((size_t)NW * 4);
    float* vd  = (float*)alloc(HH * 4);
    int* rowptr = (int*)alloc((size_t)(NW + 1) * 4);
    int* cursor = (int*)alloc((size_t)NW * 4);        // doubles as deg
    int* esrc   = (int*)alloc((size_t)(E_IN + NW) * 4);
    int* bsum   = (int*)alloc(1024 * 4);
    (void)ws_size; (void)in_sizes; (void)n_in; (void)out_size;

    auto glin = [](int M) { int g = (M + 3) / 4; return g > 4096 ? 4096 : g; };

    auto run_csr = [&](const int* edges, int E, int L, int n) {
        hipMemsetAsync(cursor, 0, (size_t)n * 4, stream);
        int T = E + L;
        int nb = (n + 255) / 256;
        k_hist<<<(T + 255) / 256, 256, 0, stream>>>(edges + E, E, L, cursor);
        k_scan1<<<nb, 256, 0, stream>>>(cursor, n, rowptr, bsum);
        k_scan2<<<1, 64, 0, stream>>>(bsum, nb);
        k_scan3<<<nb, 256, 0, stream>>>(rowptr, cursor, bsum, n, T);
        k_scatter<<<(T + 255) / 256, 256, 0, stream>>>(edges, edges + E, E, L, cursor, esrc);
    };

    // ---- artist MLP: ax = relu(artist@a_w1+b1)@a_w2+b2 ----
    k_linear<DA, HH, 1, 0><<<glin(NA), HH, 0, stream>>>(artist, DA, a_w1, a_b1, hs, HH, NA);
    k_linear<HH, HH, 0, 0><<<glin(NA), HH, 0, stream>>>(hs, HH, a_w2, a_b2, ax, HH, NA);
    // ---- work MLP: wx ----
    k_linear<HH, HH, 1, 0><<<glin(NW), HH, 0, stream>>>(workf, HH, w_w1, w_b1, hs, HH, NW);
    k_linear<HH, HH, 0, 0><<<glin(NW), HH, 0, stream>>>(hs, HH, w_w2, w_b2, wx, HH, NW);

    // ---- GAT1: creates (artists -> works), out wx, ELU ----
    k_wv<<<1, HH, 0, stream>>>(cr_W, cr_ad, vd);
    k_linear<HH, HH, 0, 0><<<glin(NA), HH, 0, stream>>>(ax, HH, cr_W, nullptr, hs, HH, NA);
    k_gemv128<<<(NA + 3) / 4, 256, 0, stream>>>(hs, HH, cr_as, nullptr, ssb, NA);
    k_gemv128<<<(NW + 3) / 4, 256, 0, stream>>>(wx, HH, vd, nullptr, sdb, NW);
    run_csr(e_cr, E_CR, NA, NW);
    k_aggregate<1><<<NW, 128, 0, stream>>>(rowptr, esrc, hs, ssb, sdb, cr_b, wx, NW);

    // ---- GAT2: influences (works -> works), out wx, ELU ----
    k_linear<HH, HH, 0, 0><<<glin(NW), HH, 0, stream>>>(wx, HH, in_W, nullptr, hs, HH, NW);
    k_gemv128<<<(NW + 3) / 4, 256, 0, stream>>>(hs, HH, in_as, nullptr, ssb, NW);
    k_gemv128<<<(NW + 3) / 4, 256, 0, stream>>>(hs, HH, in_ad, nullptr, sdb, NW);
    run_csr(e_in, E_IN, NW, NW);
    k_aggregate<1><<<NW, 128, 0, stream>>>(rowptr, esrc, hs, ssb, sdb, in_b, wx, NW);

    // ---- GAT3: created_by (works -> artists), out au, NO elu ----
    k_linear<HH, HH, 0, 0><<<glin(NW), HH, 0, stream>>>(wx, HH, cr_W, nullptr, hs, HH, NW);
    k_gemv128<<<(NW + 3) / 4, 256, 0, stream>>>(hs, HH, cr_as, nullptr, ssb, NW);
    k_gemv128<<<(NA + 3) / 4, 256, 0, stream>>>(ax, HH, vd, nullptr, sdb, NA);
    run_csr(e_cb, E_CR, NA, NA);
    k_aggregate<0><<<NA, 128, 0, stream>>>(rowptr, esrc, hs, ssb, sdb, cr_b, au, NA);

    // ---- GAT4: collab (artists -> artists), out ac, ELU ----
    k_linear<HH, HH, 0, 0><<<glin(NA), HH, 0, stream>>>(au, HH, co_W, nullptr, hs, HH, NA);
    k_gemv128<<<(NA + 3) / 4, 256, 0, stream>>>(hs, HH, co_as, nullptr, ssb, NA);
    k_gemv128<<<(NA + 3) / 4, 256, 0, stream>>>(hs, HH, co_ad, nullptr, sdb, NA);
    run_csr(e_co, E_CO, NA, NA);
    k_aggregate<1><<<NA, 128, 0, stream>>>(rowptr, esrc, hs, ssb, sdb, co_b, ac, NA);

    // ---- predictor ----
    float* h1 = hs;   // [NA,256]
    k_linear<HH, 256, 0, 0><<<glin(NA), 256, 0, stream>>>(au, HH, p_w1, p_b1, h1, 256, NA);
    k_linear<HH, 256, 1, 1><<<glin(NA), 256, 0, stream>>>(ac, HH, p_w1 + 128 * 256, nullptr, h1, 256, NA);
    float* h2 = au;   // [NA,128]
    k_linear<HH, HH, 0, 0><<<glin(NA), HH, 0, stream>>>(h1, 256, p_w2, p_b2, h2, HH, NA);
    k_linear<HH, HH, 1, 1><<<glin(NA), HH, 0, stream>>>(h1 + 128, 256, p_w2 + 128 * 128, nullptr, h2, HH, NA);
    k_gemv128<<<(NA + 3) / 4, 256, 0, stream>>>(h2, HH, p_w3, p_b3, (float*)d_out, NA);
}

// Round 2
// 1221.767 us; speedup vs baseline: 1.5848x; 1.5848x over previous
//
#include <hip/hip_runtime.h>
#include <cstddef>

#define NA 20000
#define NW 100000
#define HH 128
#define DA 64
#define E_CR 400000
#define E_IN 600000
#define E_CO 300000

// ---------------- tiled fp32 GEMM: Y[M,128] = act(X[M,ldx] @ W[K,ldw(cols 0:128)] + b) ----
// BM=128 x BN=128 tile, BK=32 double-buffered in LDS, 256 threads, 8x8 micro-tile.
constexpr int GBM = 128, GBN = 128, GBK = 32;
constexpr int GXR = GBM + 4;   // padded row stride (words) for transposed X tile

template<int K, int ACT, int ACC>
__global__ __launch_bounds__(256, 2) void k_gemm(
    const float* __restrict__ X, int ldx,
    const float* __restrict__ W, int ldw,
    const float* __restrict__ bias,
    float* __restrict__ Y, int ldy, int M)
{
    __shared__ float Ws[2][GBK][GBN];
    __shared__ float Xs[2][GBK][GXR];
    const int tid = threadIdx.x;
    const int tx = tid & 15;           // col group (8 cols)
    const int ty = tid >> 4;           // row group (8 rows)
    const int col0 = tx * 8;
    const int row0 = ty * 8;
    const int blkRow = blockIdx.x * GBM;

    float acc[8][8];
#pragma unroll
    for (int i = 0; i < 8; ++i)
#pragma unroll
        for (int j = 0; j < 8; ++j) acc[i][j] = 0.f;

    auto stageW = [&](int kk, int buf) {
#pragma unroll
        for (int i = 0; i < 4; ++i) {
            int q = i * 256 + tid;           // float4 id 0..1023
            int r = q >> 5;                   // 0..31
            int c = (q & 31) * 4;             // 0..124
            float4 v = *(const float4*)(W + (size_t)(kk + r) * ldw + c);
            *(float4*)&Ws[buf][r][c] = v;
        }
    };
    auto stageX = [&](int kk, int buf) {
#pragma unroll
        for (int i = 0; i < 4; ++i) {
            int q = i * 256 + tid;           // 0..1023
            int r = q >> 3;                   // tile row 0..127
            int c = (q & 7) * 4;              // k offset 0..28
            int gr = blkRow + r; if (gr >= M) gr = M - 1;
            float4 v = *(const float4*)(X + (size_t)gr * ldx + kk + c);
            Xs[buf][c + 0][r] = v.x;
            Xs[buf][c + 1][r] = v.y;
            Xs[buf][c + 2][r] = v.z;
            Xs[buf][c + 3][r] = v.w;
        }
    };

    constexpr int S = K / GBK;
    stageW(0, 0); stageX(0, 0);
    int buf = 0;
    for (int s = 0; s < S; ++s) {
        __syncthreads();
        if (s + 1 < S) { stageW((s + 1) * GBK, buf ^ 1); stageX((s + 1) * GBK, buf ^ 1); }
#pragma unroll 8
        for (int k = 0; k < GBK; ++k) {
            float w[8], x[8];
            *(float4*)&w[0] = *(const float4*)&Ws[buf][k][col0];
            *(float4*)&w[4] = *(const float4*)&Ws[buf][k][col0 + 4];
            *(float4*)&x[0] = *(const float4*)&Xs[buf][k][row0];
            *(float4*)&x[4] = *(const float4*)&Xs[buf][k][row0 + 4];
#pragma unroll
            for (int i = 0; i < 8; ++i)
#pragma unroll
                for (int j = 0; j < 8; ++j)
                    acc[i][j] = fmaf(x[i], w[j], acc[i][j]);
        }
        buf ^= 1;
    }

    float bv[8];
    if (bias) {
        *(float4*)&bv[0] = *(const float4*)(bias + col0);
        *(float4*)&bv[4] = *(const float4*)(bias + col0 + 4);
    } else {
#pragma unroll
        for (int j = 0; j < 8; ++j) bv[j] = 0.f;
    }
#pragma unroll
    for (int i = 0; i < 8; ++i) {
        int gr = blkRow + row0 + i;
        if (gr < M) {
            float* yp = Y + (size_t)gr * ldy + col0;
            float o[8];
#pragma unroll
            for (int j = 0; j < 8; ++j) o[j] = acc[i][j] + bv[j];
            if (ACC) {
#pragma unroll
                for (int j = 0; j < 8; ++j) o[j] += yp[j];
            }
            if (ACT == 1) {
#pragma unroll
                for (int j = 0; j < 8; ++j) o[j] = o[j] > 0.f ? o[j] : 0.f;
            }
            *(float4*)yp = *(float4*)&o[0];
            *(float4*)(yp + 4) = *(float4*)&o[4];
        }
    }
}

// ---------------- gemv: out[r] = dot(X[r, 0:128], v) + bias ----------------
__global__ __launch_bounds__(256) void k_gemv128(
    const float* __restrict__ X, int ldx, const float* __restrict__ v,
    const float* __restrict__ bias, float* __restrict__ out, int M)
{
    int lane = threadIdx.x & 63;
    int w = threadIdx.x >> 6;
    int r = blockIdx.x * 4 + w;
    if (r >= M) return;
    const float* xr = X + (size_t)r * ldx;
    float s = xr[lane] * v[lane] + xr[lane + 64] * v[lane + 64];
#pragma unroll
    for (int o = 32; o; o >>= 1) s += __shfl_xor(s, o, 64);
    if (lane == 0) out[r] = s + (bias ? bias[0] : 0.f);
}

// ---------------- vd[k] = sum_j W[k][j] * a[j] ----------------
__global__ void k_wv(const float* __restrict__ W, const float* __restrict__ a,
                     float* __restrict__ vd)
{
    __shared__ float sa[HH];
    sa[threadIdx.x] = a[threadIdx.x];
    __syncthreads();
    float s = 0.f;
    for (int jj = 0; jj < HH; ++jj) s += W[(size_t)threadIdx.x * HH + jj] * sa[jj];
    vd[threadIdx.x] = s;
}

// ---------------- CSR build ----------------
__global__ void k_hist(const int* __restrict__ dst, int E, int L, int* __restrict__ deg)
{
    int i = blockIdx.x * blockDim.x + threadIdx.x;
    int T = E + L;
    if (i >= T) return;
    int d = (i < E) ? dst[i] : (i - E);
    atomicAdd(&deg[d], 1);
}

__global__ void k_scan1(const int* __restrict__ deg, int n,
                        int* __restrict__ rowptr, int* __restrict__ bsum)
{
    __shared__ int sm[256];
    int t = threadIdx.x;
    int i = blockIdx.x * 256 + t;
    int v = (i < n) ? deg[i] : 0;
    int x = v;
    sm[t] = x;
    __syncthreads();
    for (int o = 1; o < 256; o <<= 1) {
        int y = (t >= o) ? sm[t - o] : 0;
        __syncthreads();
        x += y;
        sm[t] = x;
        __syncthreads();
    }
    if (i < n) rowptr[i] = x - v;
    if (t == 255) bsum[blockIdx.x] = x;
}

__global__ void k_scan2(int* __restrict__ bsum, int nb)
{
    if (threadIdx.x || blockIdx.x) return;
    int run = 0;
    for (int b = 0; b < nb; ++b) { int t = bsum[b]; bsum[b] = run; run += t; }
}

__global__ void k_scan3(int* __restrict__ rowptr, int* __restrict__ cursor,
                        const int* __restrict__ bsum, int n, int Etot)
{
    int i = blockIdx.x * 256 + threadIdx.x;
    if (i < n) {
        int v = rowptr[i] + bsum[i >> 8];
        rowptr[i] = v;
        cursor[i] = v;
    }
    if (i == 0) rowptr[n] = Etot;
}

__global__ void k_scatter(const int* __restrict__ src, const int* __restrict__ dstp,
                          int E, int L, int* __restrict__ cursor, int* __restrict__ esrc)
{
    int i = blockIdx.x * blockDim.x + threadIdx.x;
    int T = E + L;
    if (i >= T) return;
    int s, d;
    if (i < E) { s = src[i]; d = dstp[i]; }
    else       { s = i - E;  d = i - E; }
    int p = atomicAdd(&cursor[d], 1);
    esrc[p] = s;
}

// ---------------- GAT aggregation (one block per dst node) ----------------
template<int ELU>
__global__ __launch_bounds__(128) void k_aggregate(
    const int* __restrict__ rowptr, const int* __restrict__ esrc,
    const float* __restrict__ hs, const float* __restrict__ ss,
    const float* __restrict__ sd, const float* __restrict__ bias,
    float* __restrict__ out, int n)
{
    int d = blockIdx.x;
    if (d >= n) return;
    int j = threadIdx.x;
    int i0 = rowptr[d], i1 = rowptr[d + 1];
    float sdv = sd[d];
    float den = 0.f, acc = 0.f;
    for (int i = i0; i < i1; ++i) {
        int s = esrc[i];
        float l = ss[s] + sdv;
        l = l < 0.f ? 0.2f * l : l;
        float e = __expf(l);
        den += e;
        acc += e * hs[(size_t)s * HH + j];
    }
    float o = acc / (den + 1e-16f) + bias[j];
    if (ELU) o = o > 0.f ? o : expm1f(o);
    out[(size_t)d * HH + j] = o;
}

// ---------------- launcher ----------------
extern "C" void kernel_launch(void* const* d_in, const int* in_sizes, int n_in,
                              void* d_out, int out_size, void* d_ws, size_t ws_size,
                              hipStream_t stream)
{
    const float* artist = (const float*)d_in[0];
    const float* workf  = (const float*)d_in[1];
    const float* a_w1 = (const float*)d_in[2];  const float* a_b1 = (const float*)d_in[3];
    const float* a_w2 = (const float*)d_in[4];  const float* a_b2 = (const float*)d_in[5];
    const float* w_w1 = (const float*)d_in[6];  const float* w_b1 = (const float*)d_in[7];
    const float* w_w2 = (const float*)d_in[8];  const float* w_b2 = (const float*)d_in[9];
    const float* cr_W = (const float*)d_in[10]; const float* cr_b = (const float*)d_in[11];
    const float* cr_as = (const float*)d_in[12]; const float* cr_ad = (const float*)d_in[13];
    const float* in_W = (const float*)d_in[14]; const float* in_b = (const float*)d_in[15];
    const float* in_as = (const float*)d_in[16]; const float* in_ad = (const float*)d_in[17];
    const float* co_W = (const float*)d_in[18]; const float* co_b = (const float*)d_in[19];
    const float* co_as = (const float*)d_in[20]; const float* co_ad = (const float*)d_in[21];
    const float* p_w1 = (const float*)d_in[22]; const float* p_b1 = (const float*)d_in[23];
    const float* p_w2 = (const float*)d_in[24]; const float* p_b2 = (const float*)d_in[25];
    const float* p_w3 = (const float*)d_in[26]; const float* p_b3 = (const float*)d_in[27];
    const int* e_cr = (const int*)d_in[28];
    const int* e_cb = (const int*)d_in[29];
    const int* e_in = (const int*)d_in[30];
    const int* e_co = (const int*)d_in[31];

    char* wsp = (char*)d_ws;
    size_t off = 0;
    auto alloc = [&](size_t bytes) -> void* {
        void* p = wsp + off;
        off += (bytes + 255) / 256 * 256;
        return p;
    };
    float* ax  = (float*)alloc((size_t)NA * HH * 4);
    float* wx  = (float*)alloc((size_t)NW * HH * 4);
    float* hs  = (float*)alloc((size_t)NW * HH * 4);  // also predictor h1 [NA,256]
    float* au  = (float*)alloc((size_t)NA * HH * 4);  // also predictor h2
    float* ac  = (float*)alloc((size_t)NA * HH * 4);
    float* ssb = (float*)alloc((size_t)NW * 4);
    float* sdb = (float*)alloc((size_t)NW * 4);
    float* vd  = (float*)alloc(HH * 4);
    int* rowptr = (int*)alloc((size_t)(NW + 1) * 4);
    int* cursor = (int*)alloc((size_t)NW * 4);        // doubles as deg
    int* esrc   = (int*)alloc((size_t)(E_IN + NW) * 4);
    int* bsum   = (int*)alloc(1024 * 4);
    (void)ws_size; (void)in_sizes; (void)n_in; (void)out_size;

    auto gg = [](int M) { return (M + GBM - 1) / GBM; };

    auto run_csr = [&](const int* edges, int E, int L, int n) {
        hipMemsetAsync(cursor, 0, (size_t)n * 4, stream);
        int T = E + L;
        int nb = (n + 255) / 256;
        k_hist<<<(T + 255) / 256, 256, 0, stream>>>(edges + E, E, L, cursor);
        k_scan1<<<nb, 256, 0, stream>>>(cursor, n, rowptr, bsum);
        k_scan2<<<1, 64, 0, stream>>>(bsum, nb);
        k_scan3<<<nb, 256, 0, stream>>>(rowptr, cursor, bsum, n, T);
        k_scatter<<<(T + 255) / 256, 256, 0, stream>>>(edges, edges + E, E, L, cursor, esrc);
    };

    // ---- artist MLP: ax = relu(artist@a_w1+b1)@a_w2+b2 ----
    k_gemm<DA, 1, 0><<<gg(NA), 256, 0, stream>>>(artist, DA, a_w1, HH, a_b1, hs, HH, NA);
    k_gemm<HH, 0, 0><<<gg(NA), 256, 0, stream>>>(hs, HH, a_w2, HH, a_b2, ax, HH, NA);
    // ---- work MLP: wx ----
    k_gemm<HH, 1, 0><<<gg(NW), 256, 0, stream>>>(workf, HH, w_w1, HH, w_b1, hs, HH, NW);
    k_gemm<HH, 0, 0><<<gg(NW), 256, 0, stream>>>(hs, HH, w_w2, HH, w_b2, wx, HH, NW);

    // ---- GAT1: creates (artists -> works), out wx, ELU ----
    k_wv<<<1, HH, 0, stream>>>(cr_W, cr_ad, vd);
    k_gemm<HH, 0, 0><<<gg(NA), 256, 0, stream>>>(ax, HH, cr_W, HH, nullptr, hs, HH, NA);
    k_gemv128<<<(NA + 3) / 4, 256, 0, stream>>>(hs, HH, cr_as, nullptr, ssb, NA);
    k_gemv128<<<(NW + 3) / 4, 256, 0, stream>>>(wx, HH, vd, nullptr, sdb, NW);
    run_csr(e_cr, E_CR, NA, NW);
    k_aggregate<1><<<NW, 128, 0, stream>>>(rowptr, esrc, hs, ssb, sdb, cr_b, wx, NW);

    // ---- GAT2: influences (works -> works), out wx, ELU ----
    k_gemm<HH, 0, 0><<<gg(NW), 256, 0, stream>>>(wx, HH, in_W, HH, nullptr, hs, HH, NW);
    k_gemv128<<<(NW + 3) / 4, 256, 0, stream>>>(hs, HH, in_as, nullptr, ssb, NW);
    k_gemv128<<<(NW + 3) / 4, 256, 0, stream>>>(hs, HH, in_ad, nullptr, sdb, NW);
    run_csr(e_in, E_IN, NW, NW);
    k_aggregate<1><<<NW, 128, 0, stream>>>(rowptr, esrc, hs, ssb, sdb, in_b, wx, NW);

    // ---- GAT3: created_by (works -> artists), out au, NO elu ----
    k_gemm<HH, 0, 0><<<gg(NW), 256, 0, stream>>>(wx, HH, cr_W, HH, nullptr, hs, HH, NW);
    k_gemv128<<<(NW + 3) / 4, 256, 0, stream>>>(hs, HH, cr_as, nullptr, ssb, NW);
    k_gemv128<<<(NA + 3) / 4, 256, 0, stream>>>(ax, HH, vd, nullptr, sdb, NA);
    run_csr(e_cb, E_CR, NA, NA);
    k_aggregate<0><<<NA, 128, 0, stream>>>(rowptr, esrc, hs, ssb, sdb, cr_b, au, NA);

    // ---- GAT4: collab (artists -> artists), out ac, ELU ----
    k_gemm<HH, 0, 0><<<gg(NA), 256, 0, stream>>>(au, HH, co_W, HH, nullptr, hs, HH, NA);
    k_gemv128<<<(NA + 3) / 4, 256, 0, stream>>>(hs, HH, co_as, nullptr, ssb, NA);
    k_gemv128<<<(NA + 3) / 4, 256, 0, stream>>>(hs, HH, co_ad, nullptr, sdb, NA);
    run_csr(e_co, E_CO, NA, NA);
    k_aggregate<1><<<NA, 128, 0, stream>>>(rowptr, esrc, hs, ssb, sdb, co_b, ac, NA);

    // ---- predictor (N=256 retiled into two N=128 halves, ldw=256) ----
    float* h1 = hs;   // [NA,256]
    for (int h = 0; h < 2; ++h) {
        k_gemm<HH, 0, 0><<<gg(NA), 256, 0, stream>>>(au, HH, p_w1 + h * 128, 256, p_b1 + h * 128, h1 + h * 128, 256, NA);
        k_gemm<HH, 1, 1><<<gg(NA), 256, 0, stream>>>(ac, HH, p_w1 + 128 * 256 + h * 128, 256, nullptr, h1 + h * 128, 256, NA);
    }
    float* h2 = au;   // [NA,128]
    k_gemm<HH, 0, 0><<<gg(NA), 256, 0, stream>>>(h1, 256, p_w2, HH, p_b2, h2, HH, NA);
    k_gemm<HH, 1, 1><<<gg(NA), 256, 0, stream>>>(h1 + 128, 256, p_w2 + 128 * 128, HH, nullptr, h2, HH, NA);
    k_gemv128<<<(NA + 3) / 4, 256, 0, stream>>>(h2, HH, p_w3, p_b3, (float*)d_out, NA);
}

// Round 3
// 1138.888 us; speedup vs baseline: 1.7001x; 1.0728x over previous
//
#include <hip/hip_runtime.h>
#include <cstddef>

#define NA 20000
#define NW 100000
#define HH 128
#define DA 64
#define E_CR 400000
#define E_IN 600000
#define E_CO 300000

// ---------------- tiled fp32 GEMM: Y[M,128] = act(X[M,ldx] @ W[K,ldw(cols 0:128)] + b) ----
// BM=128 x BN=128 tile, BK=32 double-buffered in LDS, 256 threads, 8x8 micro-tile.
constexpr int GBM = 128, GBN = 128, GBK = 32;
constexpr int GXR = GBM + 4;   // padded row stride (words) for transposed X tile

template<int K, int ACT, int ACC>
__global__ __launch_bounds__(256, 2) void k_gemm(
    const float* __restrict__ X, int ldx,
    const float* __restrict__ W, int ldw,
    const float* __restrict__ bias,
    float* __restrict__ Y, int ldy, int M)
{
    __shared__ float Ws[2][GBK][GBN];
    __shared__ float Xs[2][GBK][GXR];
    const int tid = threadIdx.x;
    const int tx = tid & 15;           // col group (8 cols)
    const int ty = tid >> 4;           // row group (8 rows)
    const int col0 = tx * 8;
    const int row0 = ty * 8;
    const int blkRow = blockIdx.x * GBM;

    float acc[8][8];
#pragma unroll
    for (int i = 0; i < 8; ++i)
#pragma unroll
        for (int j = 0; j < 8; ++j) acc[i][j] = 0.f;

    auto stageW = [&](int kk, int buf) {
#pragma unroll
        for (int i = 0; i < 4; ++i) {
            int q = i * 256 + tid;           // float4 id 0..1023
            int r = q >> 5;                   // 0..31
            int c = (q & 31) * 4;             // 0..124
            float4 v = *(const float4*)(W + (size_t)(kk + r) * ldw + c);
            *(float4*)&Ws[buf][r][c] = v;
        }
    };
    auto stageX = [&](int kk, int buf) {
#pragma unroll
        for (int i = 0; i < 4; ++i) {
            int q = i * 256 + tid;           // 0..1023
            int r = q >> 3;                   // tile row 0..127
            int c = (q & 7) * 4;              // k offset 0..28
            int gr = blkRow + r; if (gr >= M) gr = M - 1;
            float4 v = *(const float4*)(X + (size_t)gr * ldx + kk + c);
            Xs[buf][c + 0][r] = v.x;
            Xs[buf][c + 1][r] = v.y;
            Xs[buf][c + 2][r] = v.z;
            Xs[buf][c + 3][r] = v.w;
        }
    };

    constexpr int S = K / GBK;
    stageW(0, 0); stageX(0, 0);
    int buf = 0;
    for (int s = 0; s < S; ++s) {
        __syncthreads();
        if (s + 1 < S) { stageW((s + 1) * GBK, buf ^ 1); stageX((s + 1) * GBK, buf ^ 1); }
#pragma unroll 8
        for (int k = 0; k < GBK; ++k) {
            float w[8], x[8];
            *(float4*)&w[0] = *(const float4*)&Ws[buf][k][col0];
            *(float4*)&w[4] = *(const float4*)&Ws[buf][k][col0 + 4];
            *(float4*)&x[0] = *(const float4*)&Xs[buf][k][row0];
            *(float4*)&x[4] = *(const float4*)&Xs[buf][k][row0 + 4];
#pragma unroll
            for (int i = 0; i < 8; ++i)
#pragma unroll
                for (int j = 0; j < 8; ++j)
                    acc[i][j] = fmaf(x[i], w[j], acc[i][j]);
        }
        buf ^= 1;
    }

    float bv[8];
    if (bias) {
        *(float4*)&bv[0] = *(const float4*)(bias + col0);
        *(float4*)&bv[4] = *(const float4*)(bias + col0 + 4);
    } else {
#pragma unroll
        for (int j = 0; j < 8; ++j) bv[j] = 0.f;
    }
#pragma unroll
    for (int i = 0; i < 8; ++i) {
        int gr = blkRow + row0 + i;
        if (gr < M) {
            float* yp = Y + (size_t)gr * ldy + col0;
            float o[8];
#pragma unroll
            for (int j = 0; j < 8; ++j) o[j] = acc[i][j] + bv[j];
            if (ACC) {
#pragma unroll
                for (int j = 0; j < 8; ++j) o[j] += yp[j];
            }
            if (ACT == 1) {
#pragma unroll
                for (int j = 0; j < 8; ++j) o[j] = o[j] > 0.f ? o[j] : 0.f;
            }
            *(float4*)yp = *(float4*)&o[0];
            *(float4*)(yp + 4) = *(float4*)&o[4];
        }
    }
}

// ---------------- gemv: out[r] = dot(X[r, 0:128], v) + bias ----------------
__global__ __launch_bounds__(256) void k_gemv128(
    const float* __restrict__ X, int ldx, const float* __restrict__ v,
    const float* __restrict__ bias, float* __restrict__ out, int M)
{
    int lane = threadIdx.x & 63;
    int w = threadIdx.x >> 6;
    int r = blockIdx.x * 4 + w;
    if (r >= M) return;
    const float* xr = X + (size_t)r * ldx;
    float s = xr[lane] * v[lane] + xr[lane + 64] * v[lane + 64];
#pragma unroll
    for (int o = 32; o; o >>= 1) s += __shfl_xor(s, o, 64);
    if (lane == 0) out[r] = s + (bias ? bias[0] : 0.f);
}

// ---------------- vd[k] = sum_j W[k][j] * a[j] ----------------
__global__ void k_wv(const float* __restrict__ W, const float* __restrict__ a,
                     float* __restrict__ vd)
{
    __shared__ float sa[HH];
    sa[threadIdx.x] = a[threadIdx.x];
    __syncthreads();
    float s = 0.f;
    for (int jj = 0; jj < HH; ++jj) s += W[(size_t)threadIdx.x * HH + jj] * sa[jj];
    vd[threadIdx.x] = s;
}

// ---------------- CSR build ----------------
__global__ void k_hist(const int* __restrict__ dst, int E, int L, int* __restrict__ deg)
{
    int i = blockIdx.x * blockDim.x + threadIdx.x;
    int T = E + L;
    if (i >= T) return;
    int d = (i < E) ? dst[i] : (i - E);
    atomicAdd(&deg[d], 1);
}

__global__ void k_scan1(const int* __restrict__ deg, int n,
                        int* __restrict__ rowptr, int* __restrict__ bsum)
{
    __shared__ int sm[256];
    int t = threadIdx.x;
    int i = blockIdx.x * 256 + t;
    int v = (i < n) ? deg[i] : 0;
    int x = v;
    sm[t] = x;
    __syncthreads();
    for (int o = 1; o < 256; o <<= 1) {
        int y = (t >= o) ? sm[t - o] : 0;
        __syncthreads();
        x += y;
        sm[t] = x;
        __syncthreads();
    }
    if (i < n) rowptr[i] = x - v;
    if (t == 255) bsum[blockIdx.x] = x;
}

__global__ void k_scan2(int* __restrict__ bsum, int nb)
{
    if (threadIdx.x || blockIdx.x) return;
    int run = 0;
    for (int b = 0; b < nb; ++b) { int t = bsum[b]; bsum[b] = run; run += t; }
}

__global__ void k_scan3(int* __restrict__ rowptr, int* __restrict__ cursor,
                        const int* __restrict__ bsum, int n, int Etot)
{
    int i = blockIdx.x * 256 + threadIdx.x;
    if (i < n) {
        int v = rowptr[i] + bsum[i >> 8];
        rowptr[i] = v;
        cursor[i] = v;
    }
    if (i == 0) rowptr[n] = Etot;
}

__global__ void k_scatter(const int* __restrict__ src, const int* __restrict__ dstp,
                          int E, int L, int* __restrict__ cursor, int* __restrict__ esrc)
{
    int i = blockIdx.x * blockDim.x + threadIdx.x;
    int T = E + L;
    if (i >= T) return;
    int s, d;
    if (i < E) { s = src[i]; d = dstp[i]; }
    else       { s = i - E;  d = i - E; }
    int p = atomicAdd(&cursor[d], 1);
    esrc[p] = s;
}

// ---------------- GAT aggregation (one block per dst node) ----------------
// U-way unrolled edge loop: U gathers in flight per wave for latency hiding.
template<int ELU, int U>
__global__ __launch_bounds__(128) void k_aggregate(
    const int* __restrict__ rowptr, const int* __restrict__ esrc,
    const float* __restrict__ hs, const float* __restrict__ ss,
    const float* __restrict__ sd, const float* __restrict__ bias,
    float* __restrict__ out, int n)
{
    int d = blockIdx.x;
    if (d >= n) return;
    int j = threadIdx.x;
    int i0 = rowptr[d], i1 = rowptr[d + 1];
    float sdv = sd[d];
    float den = 0.f, acc = 0.f;
    int i = i0;
    for (; i + U <= i1; i += U) {
        int s[U]; float h[U]; float sv[U];
#pragma unroll
        for (int u = 0; u < U; ++u) s[u] = esrc[i + u];
#pragma unroll
        for (int u = 0; u < U; ++u) h[u] = hs[(size_t)s[u] * HH + j];
#pragma unroll
        for (int u = 0; u < U; ++u) sv[u] = ss[s[u]];
#pragma unroll
        for (int u = 0; u < U; ++u) {
            float l = sv[u] + sdv;
            l = l < 0.f ? 0.2f * l : l;
            float e = __expf(l);
            den += e;
            acc = fmaf(e, h[u], acc);
        }
    }
    for (; i < i1; ++i) {
        int s = esrc[i];
        float l = ss[s] + sdv;
        l = l < 0.f ? 0.2f * l : l;
        float e = __expf(l);
        den += e;
        acc = fmaf(e, hs[(size_t)s * HH + j], acc);
    }
    float o = acc / (den + 1e-16f) + bias[j];
    if (ELU) o = o > 0.f ? o : expm1f(o);
    out[(size_t)d * HH + j] = o;
}

// ---------------- launcher ----------------
extern "C" void kernel_launch(void* const* d_in, const int* in_sizes, int n_in,
                              void* d_out, int out_size, void* d_ws, size_t ws_size,
                              hipStream_t stream)
{
    const float* artist = (const float*)d_in[0];
    const float* workf  = (const float*)d_in[1];
    const float* a_w1 = (const float*)d_in[2];  const float* a_b1 = (const float*)d_in[3];
    const float* a_w2 = (const float*)d_in[4];  const float* a_b2 = (const float*)d_in[5];
    const float* w_w1 = (const float*)d_in[6];  const float* w_b1 = (const float*)d_in[7];
    const float* w_w2 = (const float*)d_in[8];  const float* w_b2 = (const float*)d_in[9];
    const float* cr_W = (const float*)d_in[10]; const float* cr_b = (const float*)d_in[11];
    const float* cr_as = (const float*)d_in[12]; const float* cr_ad = (const float*)d_in[13];
    const float* in_W = (const float*)d_in[14]; const float* in_b = (const float*)d_in[15];
    const float* in_as = (const float*)d_in[16]; const float* in_ad = (const float*)d_in[17];
    const float* co_W = (const float*)d_in[18]; const float* co_b = (const float*)d_in[19];
    const float* co_as = (const float*)d_in[20]; const float* co_ad = (const float*)d_in[21];
    const float* p_w1 = (const float*)d_in[22]; const float* p_b1 = (const float*)d_in[23];
    const float* p_w2 = (const float*)d_in[24]; const float* p_b2 = (const float*)d_in[25];
    const float* p_w3 = (const float*)d_in[26]; const float* p_b3 = (const float*)d_in[27];
    const int* e_cr = (const int*)d_in[28];
    const int* e_cb = (const int*)d_in[29];
    const int* e_in = (const int*)d_in[30];
    const int* e_co = (const int*)d_in[31];

    char* wsp = (char*)d_ws;
    size_t off = 0;
    auto alloc = [&](size_t bytes) -> void* {
        void* p = wsp + off;
        off += (bytes + 255) / 256 * 256;
        return p;
    };
    float* ax  = (float*)alloc((size_t)NA * HH * 4);
    float* wx  = (float*)alloc((size_t)NW * HH * 4);
    float* hs  = (float*)alloc((size_t)NW * HH * 4);  // also predictor h1 [NA,256]
    float* au  = (float*)alloc((size_t)NA * HH * 4);  // also predictor h2
    float* ac  = (float*)alloc((size_t)NA * HH * 4);
    float* ssb = (float*)alloc((size_t)NW * 4);
    float* sdb = (float*)alloc((size_t)NW * 4);
    float* vd  = (float*)alloc(HH * 4);
    int* rowptr = (int*)alloc((size_t)(NW + 1) * 4);
    int* cursor = (int*)alloc((size_t)NW * 4);        // doubles as deg
    int* esrc   = (int*)alloc((size_t)(E_IN + NW) * 4);
    int* bsum   = (int*)alloc(1024 * 4);
    (void)ws_size; (void)in_sizes; (void)n_in; (void)out_size;

    auto gg = [](int M) { return (M + GBM - 1) / GBM; };

    auto run_csr = [&](const int* edges, int E, int L, int n) {
        hipMemsetAsync(cursor, 0, (size_t)n * 4, stream);
        int T = E + L;
        int nb = (n + 255) / 256;
        k_hist<<<(T + 255) / 256, 256, 0, stream>>>(edges + E, E, L, cursor);
        k_scan1<<<nb, 256, 0, stream>>>(cursor, n, rowptr, bsum);
        k_scan2<<<1, 64, 0, stream>>>(bsum, nb);
        k_scan3<<<nb, 256, 0, stream>>>(rowptr, cursor, bsum, n, T);
        k_scatter<<<(T + 255) / 256, 256, 0, stream>>>(edges, edges + E, E, L, cursor, esrc);
    };

    // ---- artist MLP: ax = relu(artist@a_w1+b1)@a_w2+b2 ----
    k_gemm<DA, 1, 0><<<gg(NA), 256, 0, stream>>>(artist, DA, a_w1, HH, a_b1, hs, HH, NA);
    k_gemm<HH, 0, 0><<<gg(NA), 256, 0, stream>>>(hs, HH, a_w2, HH, a_b2, ax, HH, NA);
    // ---- work MLP: wx ----
    k_gemm<HH, 1, 0><<<gg(NW), 256, 0, stream>>>(workf, HH, w_w1, HH, w_b1, hs, HH, NW);
    k_gemm<HH, 0, 0><<<gg(NW), 256, 0, stream>>>(hs, HH, w_w2, HH, w_b2, wx, HH, NW);

    // ---- GAT1: creates (artists -> works), out wx, ELU ----
    k_wv<<<1, HH, 0, stream>>>(cr_W, cr_ad, vd);
    k_gemm<HH, 0, 0><<<gg(NA), 256, 0, stream>>>(ax, HH, cr_W, HH, nullptr, hs, HH, NA);
    k_gemv128<<<(NA + 3) / 4, 256, 0, stream>>>(hs, HH, cr_as, nullptr, ssb, NA);
    k_gemv128<<<(NW + 3) / 4, 256, 0, stream>>>(wx, HH, vd, nullptr, sdb, NW);
    run_csr(e_cr, E_CR, NA, NW);
    k_aggregate<1, 4><<<NW, 128, 0, stream>>>(rowptr, esrc, hs, ssb, sdb, cr_b, wx, NW);

    // ---- GAT2: influences (works -> works), out wx, ELU ----
    k_gemm<HH, 0, 0><<<gg(NW), 256, 0, stream>>>(wx, HH, in_W, HH, nullptr, hs, HH, NW);
    k_gemv128<<<(NW + 3) / 4, 256, 0, stream>>>(hs, HH, in_as, nullptr, ssb, NW);
    k_gemv128<<<(NW + 3) / 4, 256, 0, stream>>>(hs, HH, in_ad, nullptr, sdb, NW);
    run_csr(e_in, E_IN, NW, NW);
    k_aggregate<1, 4><<<NW, 128, 0, stream>>>(rowptr, esrc, hs, ssb, sdb, in_b, wx, NW);

    // ---- GAT3: created_by (works -> artists), out au, NO elu ----
    k_gemm<HH, 0, 0><<<gg(NW), 256, 0, stream>>>(wx, HH, cr_W, HH, nullptr, hs, HH, NW);
    k_gemv128<<<(NW + 3) / 4, 256, 0, stream>>>(hs, HH, cr_as, nullptr, ssb, NW);
    k_gemv128<<<(NA + 3) / 4, 256, 0, stream>>>(ax, HH, vd, nullptr, sdb, NA);
    run_csr(e_cb, E_CR, NA, NA);
    k_aggregate<0, 8><<<NA, 128, 0, stream>>>(rowptr, esrc, hs, ssb, sdb, cr_b, au, NA);

    // ---- GAT4: collab (artists -> artists), out ac, ELU ----
    k_gemm<HH, 0, 0><<<gg(NA), 256, 0, stream>>>(au, HH, co_W, HH, nullptr, hs, HH, NA);
    k_gemv128<<<(NA + 3) / 4, 256, 0, stream>>>(hs, HH, co_as, nullptr, ssb, NA);
    k_gemv128<<<(NA + 3) / 4, 256, 0, stream>>>(hs, HH, co_ad, nullptr, sdb, NA);
    run_csr(e_co, E_CO, NA, NA);
    k_aggregate<1, 8><<<NA, 128, 0, stream>>>(rowptr, esrc, hs, ssb, sdb, co_b, ac, NA);

    // ---- predictor (N=256 retiled into two N=128 halves, ldw=256) ----
    float* h1 = hs;   // [NA,256]
    for (int h = 0; h < 2; ++h) {
        k_gemm<HH, 0, 0><<<gg(NA), 256, 0, stream>>>(au, HH, p_w1 + h * 128, 256, p_b1 + h * 128, h1 + h * 128, 256, NA);
        k_gemm<HH, 1, 1><<<gg(NA), 256, 0, stream>>>(ac, HH, p_w1 + 128 * 256 + h * 128, 256, nullptr, h1 + h * 128, 256, NA);
    }
    float* h2 = au;   // [NA,128]
    k_gemm<HH, 0, 0><<<gg(NA), 256, 0, stream>>>(h1, 256, p_w2, HH, p_b2, h2, HH, NA);
    k_gemm<HH, 1, 1><<<gg(NA), 256, 0, stream>>>(h1 + 128, 256, p_w2 + 128 * 128, HH, nullptr, h2, HH, NA);
    k_gemv128<<<(NA + 3) / 4, 256, 0, stream>>>(h2, HH, p_w3, p_b3, (float*)d_out, NA);
}

// Round 4
// 976.427 us; speedup vs baseline: 1.9830x; 1.1664x over previous
//
#include <hip/hip_runtime.h>
#include <cstddef>

#define NA 20000
#define NW 100000
#define HH 128
#define DA 64
#define E_CR 400000
#define E_IN 600000
#define E_CO 300000

// combined CSR arena: rows G1(NW) G2(NW) G3(NA) G4(NA)
#define ROW1 0
#define ROW2 (NW)
#define ROW3 (2 * NW)
#define ROW4 (2 * NW + NA)
#define NTOT (2 * NW + 2 * NA)
#define T1 (E_CR + NA)
#define T2 (E_IN + NW)
#define T3 (E_CR + NA)
#define T4 (E_CO + NA)
#define ETOT (T1 + T2 + T3 + T4)

// ---------------- tiled fp32 GEMM: Y[M,128] = act(X[M,ldx] @ W[K,ldw(cols 0:128)] + b) ----
constexpr int GBM = 128, GBN = 128, GBK = 32;
constexpr int GXR = GBM + 4;

template<int K, int ACT, int ACC>
__global__ __launch_bounds__(256, 2) void k_gemm(
    const float* __restrict__ X, int ldx,
    const float* __restrict__ W, int ldw,
    const float* __restrict__ bias,
    float* __restrict__ Y, int ldy, int M)
{
    __shared__ float Ws[2][GBK][GBN];
    __shared__ float Xs[2][GBK][GXR];
    const int tid = threadIdx.x;
    const int tx = tid & 15;
    const int ty = tid >> 4;
    const int col0 = tx * 8;
    const int row0 = ty * 8;
    const int blkRow = blockIdx.x * GBM;

    float acc[8][8];
#pragma unroll
    for (int i = 0; i < 8; ++i)
#pragma unroll
        for (int j = 0; j < 8; ++j) acc[i][j] = 0.f;

    auto stageW = [&](int kk, int buf) {
#pragma unroll
        for (int i = 0; i < 4; ++i) {
            int q = i * 256 + tid;
            int r = q >> 5;
            int c = (q & 31) * 4;
            float4 v = *(const float4*)(W + (size_t)(kk + r) * ldw + c);
            *(float4*)&Ws[buf][r][c] = v;
        }
    };
    auto stageX = [&](int kk, int buf) {
#pragma unroll
        for (int i = 0; i < 4; ++i) {
            int q = i * 256 + tid;
            int r = q >> 3;
            int c = (q & 7) * 4;
            int gr = blkRow + r; if (gr >= M) gr = M - 1;
            float4 v = *(const float4*)(X + (size_t)gr * ldx + kk + c);
            Xs[buf][c + 0][r] = v.x;
            Xs[buf][c + 1][r] = v.y;
            Xs[buf][c + 2][r] = v.z;
            Xs[buf][c + 3][r] = v.w;
        }
    };

    constexpr int S = K / GBK;
    stageW(0, 0); stageX(0, 0);
    int buf = 0;
    for (int s = 0; s < S; ++s) {
        __syncthreads();
        if (s + 1 < S) { stageW((s + 1) * GBK, buf ^ 1); stageX((s + 1) * GBK, buf ^ 1); }
#pragma unroll 8
        for (int k = 0; k < GBK; ++k) {
            float w[8], x[8];
            *(float4*)&w[0] = *(const float4*)&Ws[buf][k][col0];
            *(float4*)&w[4] = *(const float4*)&Ws[buf][k][col0 + 4];
            *(float4*)&x[0] = *(const float4*)&Xs[buf][k][row0];
            *(float4*)&x[4] = *(const float4*)&Xs[buf][k][row0 + 4];
#pragma unroll
            for (int i = 0; i < 8; ++i)
#pragma unroll
                for (int j = 0; j < 8; ++j)
                    acc[i][j] = fmaf(x[i], w[j], acc[i][j]);
        }
        buf ^= 1;
    }

    float bv[8];
    if (bias) {
        *(float4*)&bv[0] = *(const float4*)(bias + col0);
        *(float4*)&bv[4] = *(const float4*)(bias + col0 + 4);
    } else {
#pragma unroll
        for (int j = 0; j < 8; ++j) bv[j] = 0.f;
    }
#pragma unroll
    for (int i = 0; i < 8; ++i) {
        int gr = blkRow + row0 + i;
        if (gr < M) {
            float* yp = Y + (size_t)gr * ldy + col0;
            float o[8];
#pragma unroll
            for (int j = 0; j < 8; ++j) o[j] = acc[i][j] + bv[j];
            if (ACC) {
#pragma unroll
                for (int j = 0; j < 8; ++j) o[j] += yp[j];
            }
            if (ACT == 1) {
#pragma unroll
                for (int j = 0; j < 8; ++j) o[j] = o[j] > 0.f ? o[j] : 0.f;
            }
            *(float4*)yp = *(float4*)&o[0];
            *(float4*)(yp + 4) = *(float4*)&o[4];
        }
    }
}

// ---------------- gemv: out[r] = dot(X[r,0:128], v) (+bias) ----------------
__global__ __launch_bounds__(256) void k_gemv128(
    const float* __restrict__ X, int ldx, const float* __restrict__ v,
    const float* __restrict__ bias, float* __restrict__ out, int M)
{
    int lane = threadIdx.x & 63;
    int w = threadIdx.x >> 6;
    int r = blockIdx.x * 4 + w;
    if (r >= M) return;
    const float* xr = X + (size_t)r * ldx;
    float s = xr[lane] * v[lane] + xr[lane + 64] * v[lane + 64];
#pragma unroll
    for (int o = 32; o; o >>= 1) s += __shfl_xor(s, o, 64);
    if (lane == 0) out[r] = s + (bias ? bias[0] : 0.f);
}

// dual gemv: one pass over X computing dots with v1 and v2
__global__ __launch_bounds__(256) void k_gemv128x2(
    const float* __restrict__ X, int ldx,
    const float* __restrict__ v1, const float* __restrict__ v2,
    float* __restrict__ o1, float* __restrict__ o2, int M)
{
    int lane = threadIdx.x & 63;
    int w = threadIdx.x >> 6;
    int r = blockIdx.x * 4 + w;
    if (r >= M) return;
    const float* xr = X + (size_t)r * ldx;
    float a = xr[lane], b = xr[lane + 64];
    float s1 = a * v1[lane] + b * v1[lane + 64];
    float s2 = a * v2[lane] + b * v2[lane + 64];
#pragma unroll
    for (int o = 32; o; o >>= 1) { s1 += __shfl_xor(s1, o, 64); s2 += __shfl_xor(s2, o, 64); }
    if (lane == 0) { o1[r] = s1; o2[r] = s2; }
}

// ---------------- vd[k] = sum_j W[k][j] * a[j] ----------------
__global__ void k_wv(const float* __restrict__ W, const float* __restrict__ a,
                     float* __restrict__ vd)
{
    __shared__ float sa[HH];
    sa[threadIdx.x] = a[threadIdx.x];
    __syncthreads();
    float s = 0.f;
    for (int jj = 0; jj < HH; ++jj) s += W[(size_t)threadIdx.x * HH + jj] * sa[jj];
    vd[threadIdx.x] = s;
}

// ---------------- CSR build (combined arena) ----------------
__global__ void k_hist(const int* __restrict__ dst, int E, int L, int* __restrict__ deg)
{
    int i = blockIdx.x * blockDim.x + threadIdx.x;
    int T = E + L;
    if (i >= T) return;
    int d = (i < E) ? dst[i] : (i - E);
    atomicAdd(&deg[d], 1);
}

__global__ void k_scan1(const int* __restrict__ deg, int n,
                        int* __restrict__ rowptr, int* __restrict__ bsum)
{
    __shared__ int sm[256];
    int t = threadIdx.x;
    int i = blockIdx.x * 256 + t;
    int v = (i < n) ? deg[i] : 0;
    int x = v;
    sm[t] = x;
    __syncthreads();
    for (int o = 1; o < 256; o <<= 1) {
        int y = (t >= o) ? sm[t - o] : 0;
        __syncthreads();
        x += y;
        sm[t] = x;
        __syncthreads();
    }
    if (i < n) rowptr[i] = x - v;
    if (t == 255) bsum[blockIdx.x] = x;
}

// single-block scan of up to 1024 block sums
__global__ void k_scan2(int* __restrict__ bsum, int nb)
{
    __shared__ int sm[256];
    int t = threadIdx.x;
    int base = t * 4;
    int v[4];
    int s = 0;
#pragma unroll
    for (int q = 0; q < 4; ++q) {
        int val = (base + q < nb) ? bsum[base + q] : 0;
        v[q] = s;          // local exclusive prefix
        s += val;
    }
    int x = s;
    sm[t] = x;
    __syncthreads();
    for (int o = 1; o < 256; o <<= 1) {
        int y = (t >= o) ? sm[t - o] : 0;
        __syncthreads();
        x += y;
        sm[t] = x;
        __syncthreads();
    }
    int excl = x - s;      // exclusive prefix of this thread's chunk
#pragma unroll
    for (int q = 0; q < 4; ++q)
        if (base + q < nb) bsum[base + q] = excl + v[q];
}

__global__ void k_scan3(int* __restrict__ rowptr, int* __restrict__ cursor,
                        const int* __restrict__ bsum, int n, int Etot)
{
    int i = blockIdx.x * 256 + threadIdx.x;
    if (i < n) {
        int v = rowptr[i] + bsum[i >> 8];
        rowptr[i] = v;
        cursor[i] = v;
    }
    if (i == 0) rowptr[n] = Etot;
}

__global__ void k_scatter(const int* __restrict__ src, const int* __restrict__ dstp,
                          int E, int L, int* __restrict__ cursor, int* __restrict__ esrc)
{
    int i = blockIdx.x * blockDim.x + threadIdx.x;
    int T = E + L;
    if (i >= T) return;
    int s, d;
    if (i < E) { s = src[i]; d = dstp[i]; }
    else       { s = i - E;  d = i - E; }
    int p = atomicAdd(&cursor[d], 1);
    esrc[p] = s;
}

// ---------------- GAT aggregation: one dst per wave, float4/lane, 2 edges per pass ----
template<int ELU, int U>
__global__ __launch_bounds__(256) void k_aggregate(
    const int* __restrict__ rowptr, const int* __restrict__ esrc,
    const float* __restrict__ hs, const float* __restrict__ ss,
    const float* __restrict__ sd, const float* __restrict__ bias,
    float* __restrict__ out, int n)
{
    int lane = threadIdx.x & 63;
    int wv = threadIdx.x >> 6;
    int d = blockIdx.x * 4 + wv;
    if (d >= n) return;
    int half = lane >> 5;            // which of 2 concurrent edges
    int col = (lane & 31) * 4;       // 32 lanes x float4 = 128 cols
    int i0 = rowptr[d], i1 = rowptr[d + 1];
    float sdv = sd[d];
    float den = 0.f;
    float ax = 0.f, ay = 0.f, az = 0.f, aw = 0.f;
    int i = i0;
    for (; i + 2 * U <= i1; i += 2 * U) {
        int s[U]; float4 h[U]; float sv[U];
#pragma unroll
        for (int u = 0; u < U; ++u) s[u] = esrc[i + 2 * u + half];
#pragma unroll
        for (int u = 0; u < U; ++u) h[u] = *(const float4*)(hs + (size_t)s[u] * HH + col);
#pragma unroll
        for (int u = 0; u < U; ++u) sv[u] = ss[s[u]];
#pragma unroll
        for (int u = 0; u < U; ++u) {
            float l = sv[u] + sdv;
            l = l < 0.f ? 0.2f * l : l;
            float e = __expf(l);
            den += e;
            ax = fmaf(e, h[u].x, ax);
            ay = fmaf(e, h[u].y, ay);
            az = fmaf(e, h[u].z, az);
            aw = fmaf(e, h[u].w, aw);
        }
    }
    for (; i < i1; i += 2) {
        int idx = i + half;
        bool act = idx < i1;
        int s = esrc[act ? idx : i];     // inactive half re-reads edge i (same lines)
        float4 h = *(const float4*)(hs + (size_t)s * HH + col);
        float l = ss[s] + sdv;
        l = l < 0.f ? 0.2f * l : l;
        float e = act ? __expf(l) : 0.f;
        den += e;
        ax = fmaf(e, h.x, ax);
        ay = fmaf(e, h.y, ay);
        az = fmaf(e, h.z, az);
        aw = fmaf(e, h.w, aw);
    }
    // combine the two halves (lane l <-> l^32 hold the same columns)
    den += __shfl_xor(den, 32, 64);
    ax += __shfl_xor(ax, 32, 64);
    ay += __shfl_xor(ay, 32, 64);
    az += __shfl_xor(az, 32, 64);
    aw += __shfl_xor(aw, 32, 64);
    if (half == 0) {
        float4 b = *(const float4*)(bias + col);
        float inv = 1.f / (den + 1e-16f);
        float o0 = ax * inv + b.x;
        float o1 = ay * inv + b.y;
        float o2 = az * inv + b.z;
        float o3 = aw * inv + b.w;
        if (ELU) {
            o0 = o0 > 0.f ? o0 : expm1f(o0);
            o1 = o1 > 0.f ? o1 : expm1f(o1);
            o2 = o2 > 0.f ? o2 : expm1f(o2);
            o3 = o3 > 0.f ? o3 : expm1f(o3);
        }
        float4 o = make_float4(o0, o1, o2, o3);
        *(float4*)(out + (size_t)d * HH + col) = o;
    }
}

// ---------------- launcher ----------------
extern "C" void kernel_launch(void* const* d_in, const int* in_sizes, int n_in,
                              void* d_out, int out_size, void* d_ws, size_t ws_size,
                              hipStream_t stream)
{
    const float* artist = (const float*)d_in[0];
    const float* workf  = (const float*)d_in[1];
    const float* a_w1 = (const float*)d_in[2];  const float* a_b1 = (const float*)d_in[3];
    const float* a_w2 = (const float*)d_in[4];  const float* a_b2 = (const float*)d_in[5];
    const float* w_w1 = (const float*)d_in[6];  const float* w_b1 = (const float*)d_in[7];
    const float* w_w2 = (const float*)d_in[8];  const float* w_b2 = (const float*)d_in[9];
    const float* cr_W = (const float*)d_in[10]; const float* cr_b = (const float*)d_in[11];
    const float* cr_as = (const float*)d_in[12]; const float* cr_ad = (const float*)d_in[13];
    const float* in_W = (const float*)d_in[14]; const float* in_b = (const float*)d_in[15];
    const float* in_as = (const float*)d_in[16]; const float* in_ad = (const float*)d_in[17];
    const float* co_W = (const float*)d_in[18]; const float* co_b = (const float*)d_in[19];
    const float* co_as = (const float*)d_in[20]; const float* co_ad = (const float*)d_in[21];
    const float* p_w1 = (const float*)d_in[22]; const float* p_b1 = (const float*)d_in[23];
    const float* p_w2 = (const float*)d_in[24]; const float* p_b2 = (const float*)d_in[25];
    const float* p_w3 = (const float*)d_in[26]; const float* p_b3 = (const float*)d_in[27];
    const int* e_cr = (const int*)d_in[28];
    const int* e_cb = (const int*)d_in[29];
    const int* e_in = (const int*)d_in[30];
    const int* e_co = (const int*)d_in[31];

    char* wsp = (char*)d_ws;
    size_t off = 0;
    auto alloc = [&](size_t bytes) -> void* {
        void* p = wsp + off;
        off += (bytes + 255) / 256 * 256;
        return p;
    };
    float* ax  = (float*)alloc((size_t)NA * HH * 4);
    float* wx  = (float*)alloc((size_t)NW * HH * 4);
    float* hs  = (float*)alloc((size_t)NW * HH * 4);  // also predictor h1 [NA,256]
    float* au  = (float*)alloc((size_t)NA * HH * 4);
    float* ac  = (float*)alloc((size_t)NA * HH * 4);
    float* ssb = (float*)alloc((size_t)NW * 4);
    float* sdb = (float*)alloc((size_t)NW * 4);
    float* vd  = (float*)alloc(HH * 4);
    int* rowptr = (int*)alloc((size_t)(NTOT + 1) * 4);
    int* cursor = (int*)alloc((size_t)NTOT * 4);      // doubles as deg
    int* esrc   = (int*)alloc((size_t)ETOT * 4);
    int* bsum   = (int*)alloc(1024 * 4);
    (void)ws_size; (void)in_sizes; (void)n_in; (void)out_size;

    auto gg = [](int M) { return (M + GBM - 1) / GBM; };

    // ---- build all 4 CSRs into one arena (edges only; no feature deps) ----
    hipMemsetAsync(cursor, 0, (size_t)NTOT * 4, stream);
    k_hist<<<(T1 + 255) / 256, 256, 0, stream>>>(e_cr + E_CR, E_CR, NA, cursor + ROW1);
    k_hist<<<(T2 + 255) / 256, 256, 0, stream>>>(e_in + E_IN, E_IN, NW, cursor + ROW2);
    k_hist<<<(T3 + 255) / 256, 256, 0, stream>>>(e_cb + E_CR, E_CR, NA, cursor + ROW3);
    k_hist<<<(T4 + 255) / 256, 256, 0, stream>>>(e_co + E_CO, E_CO, NA, cursor + ROW4);
    {
        int nb = (NTOT + 255) / 256;
        k_scan1<<<nb, 256, 0, stream>>>(cursor, NTOT, rowptr, bsum);
        k_scan2<<<1, 256, 0, stream>>>(bsum, nb);
        k_scan3<<<nb, 256, 0, stream>>>(rowptr, cursor, bsum, NTOT, ETOT);
    }
    k_scatter<<<(T1 + 255) / 256, 256, 0, stream>>>(e_cr, e_cr + E_CR, E_CR, NA, cursor + ROW1, esrc);
    k_scatter<<<(T2 + 255) / 256, 256, 0, stream>>>(e_in, e_in + E_IN, E_IN, NW, cursor + ROW2, esrc);
    k_scatter<<<(T3 + 255) / 256, 256, 0, stream>>>(e_cb, e_cb + E_CR, E_CR, NA, cursor + ROW3, esrc);
    k_scatter<<<(T4 + 255) / 256, 256, 0, stream>>>(e_co, e_co + E_CO, E_CO, NA, cursor + ROW4, esrc);

    // ---- artist MLP ----
    k_gemm<DA, 1, 0><<<gg(NA), 256, 0, stream>>>(artist, DA, a_w1, HH, a_b1, hs, HH, NA);
    k_gemm<HH, 0, 0><<<gg(NA), 256, 0, stream>>>(hs, HH, a_w2, HH, a_b2, ax, HH, NA);
    // ---- work MLP ----
    k_gemm<HH, 1, 0><<<gg(NW), 256, 0, stream>>>(workf, HH, w_w1, HH, w_b1, hs, HH, NW);
    k_gemm<HH, 0, 0><<<gg(NW), 256, 0, stream>>>(hs, HH, w_w2, HH, w_b2, wx, HH, NW);

    // ---- GAT1: creates (artists -> works), out wx, ELU ----
    k_wv<<<1, HH, 0, stream>>>(cr_W, cr_ad, vd);
    k_gemm<HH, 0, 0><<<gg(NA), 256, 0, stream>>>(ax, HH, cr_W, HH, nullptr, hs, HH, NA);
    k_gemv128<<<(NA + 3) / 4, 256, 0, stream>>>(hs, HH, cr_as, nullptr, ssb, NA);
    k_gemv128<<<(NW + 3) / 4, 256, 0, stream>>>(wx, HH, vd, nullptr, sdb, NW);
    k_aggregate<1, 2><<<(NW + 3) / 4, 256, 0, stream>>>(rowptr + ROW1, esrc, hs, ssb, sdb, cr_b, wx, NW);

    // ---- GAT2: influences (works -> works), out wx, ELU ----
    k_gemm<HH, 0, 0><<<gg(NW), 256, 0, stream>>>(wx, HH, in_W, HH, nullptr, hs, HH, NW);
    k_gemv128x2<<<(NW + 3) / 4, 256, 0, stream>>>(hs, HH, in_as, in_ad, ssb, sdb, NW);
    k_aggregate<1, 2><<<(NW + 3) / 4, 256, 0, stream>>>(rowptr + ROW2, esrc, hs, ssb, sdb, in_b, wx, NW);

    // ---- GAT3: created_by (works -> artists), out au, NO elu ----
    k_gemm<HH, 0, 0><<<gg(NW), 256, 0, stream>>>(wx, HH, cr_W, HH, nullptr, hs, HH, NW);
    k_gemv128<<<(NW + 3) / 4, 256, 0, stream>>>(hs, HH, cr_as, nullptr, ssb, NW);
    k_gemv128<<<(NA + 3) / 4, 256, 0, stream>>>(ax, HH, vd, nullptr, sdb, NA);
    k_aggregate<0, 4><<<(NA + 3) / 4, 256, 0, stream>>>(rowptr + ROW3, esrc, hs, ssb, sdb, cr_b, au, NA);

    // ---- GAT4: collab (artists -> artists), out ac, ELU ----
    k_gemm<HH, 0, 0><<<gg(NA), 256, 0, stream>>>(au, HH, co_W, HH, nullptr, hs, HH, NA);
    k_gemv128x2<<<(NA + 3) / 4, 256, 0, stream>>>(hs, HH, co_as, co_ad, ssb, sdb, NA);
    k_aggregate<1, 4><<<(NA + 3) / 4, 256, 0, stream>>>(rowptr + ROW4, esrc, hs, ssb, sdb, co_b, ac, NA);

    // ---- predictor ----
    float* h1 = hs;   // [NA,256]
    for (int h = 0; h < 2; ++h) {
        k_gemm<HH, 0, 0><<<gg(NA), 256, 0, stream>>>(au, HH, p_w1 + h * 128, 256, p_b1 + h * 128, h1 + h * 128, 256, NA);
        k_gemm<HH, 1, 1><<<gg(NA), 256, 0, stream>>>(ac, HH, p_w1 + 128 * 256 + h * 128, 256, nullptr, h1 + h * 128, 256, NA);
    }
    float* h2 = au;   // [NA,128]
    k_gemm<HH, 0, 0><<<gg(NA), 256, 0, stream>>>(h1, 256, p_w2, HH, p_b2, h2, HH, NA);
    k_gemm<HH, 1, 1><<<gg(NA), 256, 0, stream>>>(h1 + 128, 256, p_w2 + 128 * 128, HH, nullptr, h2, HH, NA);
    k_gemv128<<<(NA + 3) / 4, 256, 0, stream>>>(h2, HH, p_w3, p_b3, (float*)d_out, NA);
}

// Round 5
// 771.746 us; speedup vs baseline: 2.5089x; 1.2652x over previous
//
#include <hip/hip_runtime.h>
#include <cstddef>

#define NA 20000
#define NW 100000
#define HH 128
#define DA 64
#define E_CR 400000
#define E_IN 600000
#define E_CO 300000

// combined CSR arena: rows G1(NW) G2(NW) G3(NA) G4(NA)
#define ROW1 0
#define ROW2 (NW)
#define ROW3 (2 * NW)
#define ROW4 (2 * NW + NA)
#define NTOT (2 * NW + 2 * NA)
#define T1 (E_CR + NA)
#define T2 (E_IN + NW)
#define T3 (E_CR + NA)
#define T4 (E_CO + NA)
#define ETOT (T1 + T2 + T3 + T4)

typedef short v8s __attribute__((ext_vector_type(8)));
typedef float v4f __attribute__((ext_vector_type(4)));

constexpr int SLOT = 128 * 136;   // shorts per hi (or lo) plane, max K=128 (KP=136)

__device__ inline short f2bf(float x) {
    union { float f; unsigned u; } c; c.f = x;
    unsigned r = c.u + 0x7fff + ((c.u >> 16) & 1);   // RNE
    return (short)(r >> 16);
}
__device__ inline float bf2f(short s) {
    union { unsigned u; float f; } c; c.u = ((unsigned)(unsigned short)s) << 16;
    return c.f;
}

// ---------------- weight prep: split fp32 W[k][n] -> bf16 hi/lo, layout [n][K+8] ----------
struct PrepDesc { const float* src; int ldw; int K; };
struct PrepArgs { PrepDesc d[13]; };

__global__ __launch_bounds__(256) void k_prep(PrepArgs a, short* __restrict__ out) {
    int m = blockIdx.x >> 6;                       // 64 blocks per matrix
    int e = (blockIdx.x & 63) * 256 + threadIdx.x; // element id
    PrepDesc dd = a.d[m];
    int K = dd.K, KP = K + 8;
    if (e >= K * 128) return;
    int n = e & 127, k = e >> 7;
    float x = dd.src[(size_t)k * dd.ldw + n];
    short h = f2bf(x);
    short l = f2bf(x - bf2f(h));
    short* base = out + (size_t)m * 2 * SLOT;
    base[n * KP + k] = h;
    base[128 * KP + n * KP + k] = l;
}

// ---------------- split-bf16 MFMA GEMM: Y[M,128] = act(X[M,ldx] @ W[K,128] + b) ----------
// block = 128 rows, 4 waves x 32 rows; per wave: 2 row-frags x 8 col-frags of 16x16.
// 3-MFMA split per fragment: al*bh + ah*bl + ah*bh, fp32 accumulation.
// NSS: fused per-row dot products ss1[r]=dot(Y[r,:],v1), ss2[r]=dot(Y[r,:],v2).
template<int K, int ACT, int ACC, int NSS>
__global__ __launch_bounds__(256, 2) void k_gemm_mfma(
    const float* __restrict__ X, int ldx,
    const short* __restrict__ Wp,
    const float* __restrict__ bias,
    float* __restrict__ Y, int ldy, int M,
    const float* __restrict__ v1, float* __restrict__ ss1,
    const float* __restrict__ v2, float* __restrict__ ss2)
{
    constexpr int KF = K / 32;
    constexpr int KP = K + 8;
    __shared__ short Bs[2 * 128 * KP];
    const int tid = threadIdx.x;
    const int wave = tid >> 6, lane = tid & 63;
    const int l15 = lane & 15, quad = lane >> 4;
    const int wrow = blockIdx.x * 128 + wave * 32;

    // stage pre-split weights -> LDS, linear conflict-free float4 copy
    {
        const float4* src = (const float4*)Wp;
        float4* dst = (float4*)Bs;
        constexpr int total = 2 * 128 * KP / 8;
        for (int i = tid; i < total; i += 256) dst[i] = src[i];
    }

    // A fragments straight from global (A[m=lane&15][k=quad*8+j]), split hi/lo in regs
    v8s ah[2][KF], al[2][KF];
#pragma unroll
    for (int rf = 0; rf < 2; ++rf) {
        int r = wrow + rf * 16 + l15; if (r >= M) r = M - 1;
        const float* xp = X + (size_t)r * ldx + quad * 8;
#pragma unroll
        for (int kf = 0; kf < KF; ++kf) {
            float xv[8];
            *(float4*)&xv[0] = *(const float4*)(xp + kf * 32);
            *(float4*)&xv[4] = *(const float4*)(xp + kf * 32 + 4);
#pragma unroll
            for (int j = 0; j < 8; ++j) {
                short h = f2bf(xv[j]);
                ah[rf][kf][j] = h;
                al[rf][kf][j] = f2bf(xv[j] - bf2f(h));
            }
        }
    }
    __syncthreads();

    v4f acc[2][8];
#pragma unroll
    for (int rf = 0; rf < 2; ++rf)
#pragma unroll
        for (int cf = 0; cf < 8; ++cf) acc[rf][cf] = (v4f){0.f, 0.f, 0.f, 0.f};

#pragma unroll
    for (int kf = 0; kf < KF; ++kf) {
#pragma unroll
        for (int cf = 0; cf < 8; ++cf) {
            int coff = (cf * 16 + l15) * KP + kf * 32 + quad * 8;
            v8s bh = *(const v8s*)&Bs[coff];
            v8s bl = *(const v8s*)&Bs[128 * KP + coff];
#pragma unroll
            for (int rf = 0; rf < 2; ++rf) {
                acc[rf][cf] = __builtin_amdgcn_mfma_f32_16x16x32_bf16(al[rf][kf], bh, acc[rf][cf], 0, 0, 0);
                acc[rf][cf] = __builtin_amdgcn_mfma_f32_16x16x32_bf16(ah[rf][kf], bl, acc[rf][cf], 0, 0, 0);
                acc[rf][cf] = __builtin_amdgcn_mfma_f32_16x16x32_bf16(ah[rf][kf], bh, acc[rf][cf], 0, 0, 0);
            }
        }
    }

    float bv[8], v1c[8], v2c[8];
#pragma unroll
    for (int cf = 0; cf < 8; ++cf) {
        int col = cf * 16 + l15;
        bv[cf] = bias ? bias[col] : 0.f;
        if (NSS >= 1) v1c[cf] = v1[col];
        if (NSS >= 2) v2c[cf] = v2[col];
    }

    // epilogue: C/D layout col=lane&15, row=quad*4+reg
#pragma unroll
    for (int rf = 0; rf < 2; ++rf) {
#pragma unroll
        for (int reg = 0; reg < 4; ++reg) {
            int r = wrow + rf * 16 + quad * 4 + reg;
            if (r >= M) continue;
            float p1 = 0.f, p2 = 0.f;
            float* yp = Y + (size_t)r * ldy;
#pragma unroll
            for (int cf = 0; cf < 8; ++cf) {
                int col = cf * 16 + l15;
                float o = acc[rf][cf][reg] + bv[cf];
                if (ACC) o += yp[col];
                if (ACT == 1) o = o > 0.f ? o : 0.f;
                if (NSS >= 1) p1 = fmaf(o, v1c[cf], p1);
                if (NSS >= 2) p2 = fmaf(o, v2c[cf], p2);
                yp[col] = o;
            }
            if (NSS >= 1) {
#pragma unroll
                for (int w = 1; w < 16; w <<= 1) {
                    p1 += __shfl_xor(p1, w, 64);
                    if (NSS >= 2) p2 += __shfl_xor(p2, w, 64);
                }
                if (l15 == 0) {
                    ss1[r] = p1;
                    if (NSS >= 2) ss2[r] = p2;
                }
            }
        }
    }
}

// ---------------- gemv: out[r] = dot(X[r,0:128], v) (+bias) ----------------
__global__ __launch_bounds__(256) void k_gemv128(
    const float* __restrict__ X, int ldx, const float* __restrict__ v,
    const float* __restrict__ bias, float* __restrict__ out, int M)
{
    int lane = threadIdx.x & 63;
    int w = threadIdx.x >> 6;
    int r = blockIdx.x * 4 + w;
    if (r >= M) return;
    const float* xr = X + (size_t)r * ldx;
    float s = xr[lane] * v[lane] + xr[lane + 64] * v[lane + 64];
#pragma unroll
    for (int o = 32; o; o >>= 1) s += __shfl_xor(s, o, 64);
    if (lane == 0) out[r] = s + (bias ? bias[0] : 0.f);
}

// ---------------- vd[k] = sum_j W[k][j] * a[j] ----------------
__global__ void k_wv(const float* __restrict__ W, const float* __restrict__ a,
                     float* __restrict__ vd)
{
    __shared__ float sa[HH];
    sa[threadIdx.x] = a[threadIdx.x];
    __syncthreads();
    float s = 0.f;
    for (int jj = 0; jj < HH; ++jj) s += W[(size_t)threadIdx.x * HH + jj] * sa[jj];
    vd[threadIdx.x] = s;
}

// ---------------- CSR build (combined arena) ----------------
__global__ void k_hist(const int* __restrict__ dst, int E, int L, int* __restrict__ deg)
{
    int i = blockIdx.x * blockDim.x + threadIdx.x;
    int T = E + L;
    if (i >= T) return;
    int d = (i < E) ? dst[i] : (i - E);
    atomicAdd(&deg[d], 1);
}

__global__ void k_scan1(const int* __restrict__ deg, int n,
                        int* __restrict__ rowptr, int* __restrict__ bsum)
{
    __shared__ int sm[256];
    int t = threadIdx.x;
    int i = blockIdx.x * 256 + t;
    int v = (i < n) ? deg[i] : 0;
    int x = v;
    sm[t] = x;
    __syncthreads();
    for (int o = 1; o < 256; o <<= 1) {
        int y = (t >= o) ? sm[t - o] : 0;
        __syncthreads();
        x += y;
        sm[t] = x;
        __syncthreads();
    }
    if (i < n) rowptr[i] = x - v;
    if (t == 255) bsum[blockIdx.x] = x;
}

__global__ void k_scan2(int* __restrict__ bsum, int nb)
{
    __shared__ int sm[256];
    int t = threadIdx.x;
    int base = t * 4;
    int v[4];
    int s = 0;
#pragma unroll
    for (int q = 0; q < 4; ++q) {
        int val = (base + q < nb) ? bsum[base + q] : 0;
        v[q] = s;
        s += val;
    }
    int x = s;
    sm[t] = x;
    __syncthreads();
    for (int o = 1; o < 256; o <<= 1) {
        int y = (t >= o) ? sm[t - o] : 0;
        __syncthreads();
        x += y;
        sm[t] = x;
        __syncthreads();
    }
    int excl = x - s;
#pragma unroll
    for (int q = 0; q < 4; ++q)
        if (base + q < nb) bsum[base + q] = excl + v[q];
}

__global__ void k_scan3(int* __restrict__ rowptr, int* __restrict__ cursor,
                        const int* __restrict__ bsum, int n, int Etot)
{
    int i = blockIdx.x * 256 + threadIdx.x;
    if (i < n) {
        int v = rowptr[i] + bsum[i >> 8];
        rowptr[i] = v;
        cursor[i] = v;
    }
    if (i == 0) rowptr[n] = Etot;
}

__global__ void k_scatter(const int* __restrict__ src, const int* __restrict__ dstp,
                          int E, int L, int* __restrict__ cursor, int* __restrict__ esrc)
{
    int i = blockIdx.x * blockDim.x + threadIdx.x;
    int T = E + L;
    if (i >= T) return;
    int s, d;
    if (i < E) { s = src[i]; d = dstp[i]; }
    else       { s = i - E;  d = i - E; }
    int p = atomicAdd(&cursor[d], 1);
    esrc[p] = s;
}

// ---------------- GAT aggregation: one dst per wave, float4/lane, 2 edges per pass ----
template<int ELU, int U>
__global__ __launch_bounds__(256) void k_aggregate(
    const int* __restrict__ rowptr, const int* __restrict__ esrc,
    const float* __restrict__ hs, const float* __restrict__ ss,
    const float* __restrict__ sd, const float* __restrict__ bias,
    float* __restrict__ out, int n)
{
    int lane = threadIdx.x & 63;
    int wv = threadIdx.x >> 6;
    int d = blockIdx.x * 4 + wv;
    if (d >= n) return;
    int half = lane >> 5;
    int col = (lane & 31) * 4;
    int i0 = rowptr[d], i1 = rowptr[d + 1];
    float sdv = sd[d];
    float den = 0.f;
    float ax = 0.f, ay = 0.f, az = 0.f, aw = 0.f;
    int i = i0;
    for (; i + 2 * U <= i1; i += 2 * U) {
        int s[U]; float4 h[U]; float sv[U];
#pragma unroll
        for (int u = 0; u < U; ++u) s[u] = esrc[i + 2 * u + half];
#pragma unroll
        for (int u = 0; u < U; ++u) h[u] = *(const float4*)(hs + (size_t)s[u] * HH + col);
#pragma unroll
        for (int u = 0; u < U; ++u) sv[u] = ss[s[u]];
#pragma unroll
        for (int u = 0; u < U; ++u) {
            float l = sv[u] + sdv;
            l = l < 0.f ? 0.2f * l : l;
            float e = __expf(l);
            den += e;
            ax = fmaf(e, h[u].x, ax);
            ay = fmaf(e, h[u].y, ay);
            az = fmaf(e, h[u].z, az);
            aw = fmaf(e, h[u].w, aw);
        }
    }
    for (; i < i1; i += 2) {
        int idx = i + half;
        bool act = idx < i1;
        int s = esrc[act ? idx : i];
        float4 h = *(const float4*)(hs + (size_t)s * HH + col);
        float l = ss[s] + sdv;
        l = l < 0.f ? 0.2f * l : l;
        float e = act ? __expf(l) : 0.f;
        den += e;
        ax = fmaf(e, h.x, ax);
        ay = fmaf(e, h.y, ay);
        az = fmaf(e, h.z, az);
        aw = fmaf(e, h.w, aw);
    }
    den += __shfl_xor(den, 32, 64);
    ax += __shfl_xor(ax, 32, 64);
    ay += __shfl_xor(ay, 32, 64);
    az += __shfl_xor(az, 32, 64);
    aw += __shfl_xor(aw, 32, 64);
    if (half == 0) {
        float4 b = *(const float4*)(bias + col);
        float inv = 1.f / (den + 1e-16f);
        float o0 = ax * inv + b.x;
        float o1 = ay * inv + b.y;
        float o2 = az * inv + b.z;
        float o3 = aw * inv + b.w;
        if (ELU) {
            o0 = o0 > 0.f ? o0 : expm1f(o0);
            o1 = o1 > 0.f ? o1 : expm1f(o1);
            o2 = o2 > 0.f ? o2 : expm1f(o2);
            o3 = o3 > 0.f ? o3 : expm1f(o3);
        }
        float4 o = make_float4(o0, o1, o2, o3);
        *(float4*)(out + (size_t)d * HH + col) = o;
    }
}

// ---------------- launcher ----------------
extern "C" void kernel_launch(void* const* d_in, const int* in_sizes, int n_in,
                              void* d_out, int out_size, void* d_ws, size_t ws_size,
                              hipStream_t stream)
{
    const float* artist = (const float*)d_in[0];
    const float* workf  = (const float*)d_in[1];
    const float* a_w1 = (const float*)d_in[2];  const float* a_b1 = (const float*)d_in[3];
    const float* a_w2 = (const float*)d_in[4];  const float* a_b2 = (const float*)d_in[5];
    const float* w_w1 = (const float*)d_in[6];  const float* w_b1 = (const float*)d_in[7];
    const float* w_w2 = (const float*)d_in[8];  const float* w_b2 = (const float*)d_in[9];
    const float* cr_W = (const float*)d_in[10]; const float* cr_b = (const float*)d_in[11];
    const float* cr_as = (const float*)d_in[12]; const float* cr_ad = (const float*)d_in[13];
    const float* in_W = (const float*)d_in[14]; const float* in_b = (const float*)d_in[15];
    const float* in_as = (const float*)d_in[16]; const float* in_ad = (const float*)d_in[17];
    const float* co_W = (const float*)d_in[18]; const float* co_b = (const float*)d_in[19];
    const float* co_as = (const float*)d_in[20]; const float* co_ad = (const float*)d_in[21];
    const float* p_w1 = (const float*)d_in[22]; const float* p_b1 = (const float*)d_in[23];
    const float* p_w2 = (const float*)d_in[24]; const float* p_b2 = (const float*)d_in[25];
    const float* p_w3 = (const float*)d_in[26]; const float* p_b3 = (const float*)d_in[27];
    const int* e_cr = (const int*)d_in[28];
    const int* e_cb = (const int*)d_in[29];
    const int* e_in = (const int*)d_in[30];
    const int* e_co = (const int*)d_in[31];

    char* wsp = (char*)d_ws;
    size_t off = 0;
    auto alloc = [&](size_t bytes) -> void* {
        void* p = wsp + off;
        off += (bytes + 255) / 256 * 256;
        return p;
    };
    float* ax  = (float*)alloc((size_t)NA * HH * 4);
    float* wx  = (float*)alloc((size_t)NW * HH * 4);
    float* hs  = (float*)alloc((size_t)NW * HH * 4);  // also predictor h1 [NA,256]
    float* au  = (float*)alloc((size_t)NA * HH * 4);
    float* ac  = (float*)alloc((size_t)NA * HH * 4);
    float* ss1 = (float*)alloc((size_t)NA * 4);
    float* sd1 = (float*)alloc((size_t)NW * 4);
    float* ss2 = (float*)alloc((size_t)NW * 4);
    float* sd2 = (float*)alloc((size_t)NW * 4);
    float* ss3 = (float*)alloc((size_t)NW * 4);
    float* sd3 = (float*)alloc((size_t)NA * 4);
    float* ss4 = (float*)alloc((size_t)NA * 4);
    float* sd4 = (float*)alloc((size_t)NA * 4);
    float* vd  = (float*)alloc(HH * 4);
    int* rowptr = (int*)alloc((size_t)(NTOT + 1) * 4);
    int* cursor = (int*)alloc((size_t)NTOT * 4);
    int* esrc   = (int*)alloc((size_t)ETOT * 4);
    int* bsum   = (int*)alloc(1024 * 4);
    short* preW = (short*)alloc((size_t)13 * 2 * SLOT * 2);
    (void)ws_size; (void)in_sizes; (void)n_in; (void)out_size;

    auto pre = [&](int m) { return preW + (size_t)m * 2 * SLOT; };
    auto gg = [](int M) { return (M + 127) / 128; };

    // ---- weight prep (one launch, 13 matrices) ----
    PrepArgs pa;
    pa.d[0]  = {a_w1, HH, DA};
    pa.d[1]  = {a_w2, HH, HH};
    pa.d[2]  = {w_w1, HH, HH};
    pa.d[3]  = {w_w2, HH, HH};
    pa.d[4]  = {cr_W, HH, HH};
    pa.d[5]  = {in_W, HH, HH};
    pa.d[6]  = {co_W, HH, HH};
    pa.d[7]  = {p_w1, 256, HH};                    // rows 0-127, cols 0-127
    pa.d[8]  = {p_w1 + 128, 256, HH};              // rows 0-127, cols 128-255
    pa.d[9]  = {p_w1 + 128 * 256, 256, HH};        // rows 128-255, cols 0-127
    pa.d[10] = {p_w1 + 128 * 256 + 128, 256, HH};  // rows 128-255, cols 128-255
    pa.d[11] = {p_w2, HH, HH};                     // rows 0-127
    pa.d[12] = {p_w2 + 128 * HH, HH, HH};          // rows 128-255
    k_prep<<<13 * 64, 256, 0, stream>>>(pa, preW);
    k_wv<<<1, HH, 0, stream>>>(cr_W, cr_ad, vd);

    // ---- build all 4 CSRs into one arena ----
    hipMemsetAsync(cursor, 0, (size_t)NTOT * 4, stream);
    k_hist<<<(T1 + 255) / 256, 256, 0, stream>>>(e_cr + E_CR, E_CR, NA, cursor + ROW1);
    k_hist<<<(T2 + 255) / 256, 256, 0, stream>>>(e_in + E_IN, E_IN, NW, cursor + ROW2);
    k_hist<<<(T3 + 255) / 256, 256, 0, stream>>>(e_cb + E_CR, E_CR, NA, cursor + ROW3);
    k_hist<<<(T4 + 255) / 256, 256, 0, stream>>>(e_co + E_CO, E_CO, NA, cursor + ROW4);
    {
        int nb = (NTOT + 255) / 256;
        k_scan1<<<nb, 256, 0, stream>>>(cursor, NTOT, rowptr, bsum);
        k_scan2<<<1, 256, 0, stream>>>(bsum, nb);
        k_scan3<<<nb, 256, 0, stream>>>(rowptr, cursor, bsum, NTOT, ETOT);
    }
    k_scatter<<<(T1 + 255) / 256, 256, 0, stream>>>(e_cr, e_cr + E_CR, E_CR, NA, cursor + ROW1, esrc);
    k_scatter<<<(T2 + 255) / 256, 256, 0, stream>>>(e_in, e_in + E_IN, E_IN, NW, cursor + ROW2, esrc);
    k_scatter<<<(T3 + 255) / 256, 256, 0, stream>>>(e_cb, e_cb + E_CR, E_CR, NA, cursor + ROW3, esrc);
    k_scatter<<<(T4 + 255) / 256, 256, 0, stream>>>(e_co, e_co + E_CO, E_CO, NA, cursor + ROW4, esrc);

    // ---- artist MLP (fused: sd3 = ax @ vd for GAT3) ----
    k_gemm_mfma<DA, 1, 0, 0><<<gg(NA), 256, 0, stream>>>(artist, DA, pre(0), a_b1, hs, HH, NA, nullptr, nullptr, nullptr, nullptr);
    k_gemm_mfma<HH, 0, 0, 1><<<gg(NA), 256, 0, stream>>>(hs, HH, pre(1), a_b2, ax, HH, NA, vd, sd3, nullptr, nullptr);
    // ---- work MLP (fused: sd1 = wx @ vd for GAT1) ----
    k_gemm_mfma<HH, 1, 0, 0><<<gg(NW), 256, 0, stream>>>(workf, HH, pre(2), w_b1, hs, HH, NW, nullptr, nullptr, nullptr, nullptr);
    k_gemm_mfma<HH, 0, 0, 1><<<gg(NW), 256, 0, stream>>>(hs, HH, pre(3), w_b2, wx, HH, NW, vd, sd1, nullptr, nullptr);

    // ---- GAT1: creates (artists -> works), out wx, ELU ----
    k_gemm_mfma<HH, 0, 0, 1><<<gg(NA), 256, 0, stream>>>(ax, HH, pre(4), nullptr, hs, HH, NA, cr_as, ss1, nullptr, nullptr);
    k_aggregate<1, 2><<<(NW + 3) / 4, 256, 0, stream>>>(rowptr + ROW1, esrc, hs, ss1, sd1, cr_b, wx, NW);

    // ---- GAT2: influences (works -> works), out wx, ELU ----
    k_gemm_mfma<HH, 0, 0, 2><<<gg(NW), 256, 0, stream>>>(wx, HH, pre(5), nullptr, hs, HH, NW, in_as, ss2, in_ad, sd2);
    k_aggregate<1, 2><<<(NW + 3) / 4, 256, 0, stream>>>(rowptr + ROW2, esrc, hs, ss2, sd2, in_b, wx, NW);

    // ---- GAT3: created_by (works -> artists), out au, NO elu ----
    k_gemm_mfma<HH, 0, 0, 1><<<gg(NW), 256, 0, stream>>>(wx, HH, pre(4), nullptr, hs, HH, NW, cr_as, ss3, nullptr, nullptr);
    k_aggregate<0, 4><<<(NA + 3) / 4, 256, 0, stream>>>(rowptr + ROW3, esrc, hs, ss3, sd3, cr_b, au, NA);

    // ---- GAT4: collab (artists -> artists), out ac, ELU ----
    k_gemm_mfma<HH, 0, 0, 2><<<gg(NA), 256, 0, stream>>>(au, HH, pre(6), nullptr, hs, HH, NA, co_as, ss4, co_ad, sd4);
    k_aggregate<1, 4><<<(NA + 3) / 4, 256, 0, stream>>>(rowptr + ROW4, esrc, hs, ss4, sd4, co_b, ac, NA);

    // ---- predictor ----
    float* h1 = hs;   // [NA,256]
    k_gemm_mfma<HH, 0, 0, 0><<<gg(NA), 256, 0, stream>>>(au, HH, pre(7), p_b1, h1, 256, NA, nullptr, nullptr, nullptr, nullptr);
    k_gemm_mfma<HH, 0, 0, 0><<<gg(NA), 256, 0, stream>>>(au, HH, pre(8), p_b1 + 128, h1 + 128, 256, NA, nullptr, nullptr, nullptr, nullptr);
    k_gemm_mfma<HH, 1, 1, 0><<<gg(NA), 256, 0, stream>>>(ac, HH, pre(9), nullptr, h1, 256, NA, nullptr, nullptr, nullptr, nullptr);
    k_gemm_mfma<HH, 1, 1, 0><<<gg(NA), 256, 0, stream>>>(ac, HH, pre(10), nullptr, h1 + 128, 256, NA, nullptr, nullptr, nullptr, nullptr);
    float* h2 = au;   // [NA,128]
    k_gemm_mfma<HH, 0, 0, 0><<<gg(NA), 256, 0, stream>>>(h1, 256, pre(11), p_b2, h2, HH, NA, nullptr, nullptr, nullptr, nullptr);
    k_gemm_mfma<HH, 1, 1, 0><<<gg(NA), 256, 0, stream>>>(h1 + 128, 256, pre(12), nullptr, h2, HH, NA, nullptr, nullptr, nullptr, nullptr);
    k_gemv128<<<(NA + 3) / 4, 256, 0, stream>>>(h2, HH, p_w3, p_b3, (float*)d_out, NA);
}